// Round 1
// 154.341 us; speedup vs baseline: 1.0760x; 1.0760x over previous
//
#include <hip/hip_runtime.h>
#include <stdint.h>

#define SAMPLES   524288
#define BATCH     16
#define T_FRAMES  2048
#define K_FFT     1024
#define HOPSZ     256
#define CACHEPAD  1023
#define NCH       513
#define XROW      525312               // 1023 pad + 524288 samples + 1 spare (16B-aligned rows)

typedef __bf16          bf16x8 __attribute__((ext_vector_type(8)));
typedef float           f32x4  __attribute__((ext_vector_type(4)));
typedef unsigned short  u16x8  __attribute__((ext_vector_type(8)));

__device__ __forceinline__ unsigned short f2bf(float f) {
    union { float f; unsigned u; } v; v.f = f;
    unsigned r = v.u + 0x7fffu + ((v.u >> 16) & 1u);   // round-to-nearest-even
    return (unsigned short)(r >> 16);
}

// ---------- fused prep --------------------------------------------------
// blocks [0,512):    weight fp32 -> bf16, M=1024 layout: 32-row pairs of
//                    {16 cos rows | 16 sin rows} per bin-group; the sin(bin0)
//                    slot (row 16) holds cos(bin 512) instead (sin0 == 0).
// blocks [512,4608): x fp32 -> bf16 with 1023-zero left pad per batch row.
__global__ void prep(const float* __restrict__ x, const float* __restrict__ wsrc,
                     unsigned short* __restrict__ Xb, unsigned short* __restrict__ Wb) {
    const int bid = blockIdx.x;
    const int tid = threadIdx.x;
    if (bid < 512) {
        int gid = bid * 256 + tid;            // 0..131071, 8 u16 each
        int m   = gid >> 7;                   // 0..1023 output row
        int kc  = (gid & 127) << 3;           // k chunk base
        int q = m >> 5, h = (m >> 4) & 1, r = m & 15;
        int bin  = q * 16 + r;
        int srow = (h == 0) ? bin : (bin == 0 ? 512 : NCH + bin);
        const float* s = wsrc + (long long)srow * K_FFT + kc;
        f32x4 a = *(const f32x4*)s;
        f32x4 c = *(const f32x4*)(s + 4);
        union { u16x8 v; unsigned short e[8]; } o;
        o.e[0]=f2bf(a[0]); o.e[1]=f2bf(a[1]); o.e[2]=f2bf(a[2]); o.e[3]=f2bf(a[3]);
        o.e[4]=f2bf(c[0]); o.e[5]=f2bf(c[1]); o.e[6]=f2bf(c[2]); o.e[7]=f2bf(c[3]);
        *(u16x8*)(Wb + (long long)m * K_FFT + kc) = o.v;
    } else {
        int id  = bid - 512;
        int bat = id >> 8;
        int bx  = id & 255;
        unsigned short* xbo = Xb + (long long)bat * XROW;
        if (bx == 0) {
            for (int j = tid; j < CACHEPAD; j += 256) xbo[j] = 0;
            if (tid == 0) xbo[XROW - 1] = 0;
        }
        int i0 = (bx * 256 + tid) * 8;
        const float* xb = x + (long long)bat * SAMPLES;
        f32x4 a = *(const f32x4*)&xb[i0];
        f32x4 c = *(const f32x4*)&xb[i0 + 4];
        unsigned short* dst = xbo + CACHEPAD + i0;
        dst[0]=f2bf(a[0]); dst[1]=f2bf(a[1]); dst[2]=f2bf(a[2]); dst[3]=f2bf(a[3]);
        dst[4]=f2bf(c[0]); dst[5]=f2bf(c[1]); dst[6]=f2bf(c[2]); dst[7]=f2bf(c[3]);
    }
}

// ---------- async global -> LDS (16 B/lane, dst = wave-uniform base + lane*16)
__device__ __forceinline__ void gll16(const unsigned short* g, unsigned short* s) {
    __builtin_amdgcn_global_load_lds(
        (const __attribute__((address_space(1))) void*)g,
        (__attribute__((address_space(3))) void*)s,
        16, 0, 0);
}

#define MFMA(a,b,c) __builtin_amdgcn_mfma_f32_16x16x32_bf16((a),(b),(c),0,0,0)

// ---------- main GEMM: 256x256 tile, BK=64, 8 waves (2M x 4N), 8-phase ----
// LDS 128KB = 2 bufs x 4 half-tiles(16KB): [A-k0 | B-k0 | A-k1 | B-k1].
// Half-tile layout: [256 rows][32 k] u16, 64B rows, chunk(16B) ^= (row>>1)&3
// (pre-swizzled on the global source; <=2-way bank aliasing on ds_read_b128).
// Schedule: phase p of K-tile j stages half-tiles with lead 6 phases:
//   P0: t(j+1) A-k1   P1: t(j+1) B-k1   P2: t(j+2) A-k0   P3: t(j+2) B-k0
// vmcnt(4) once per tile (end of P3) leaves exactly t(j+2){A-k0,B-k0} in
// flight and guarantees all of tile j+1; vmcnt(0) only at j==14 (prefetch
// stops). Each phase: reads -> stage -> barrier -> setprio(1) 16xMFMA -> barrier.
__global__ __launch_bounds__(512, 2)
void stft_gemm(const unsigned short* __restrict__ Xb,
               const unsigned short* __restrict__ Wb,
               float* __restrict__ out) {
    __shared__ unsigned short S[65536];      // 128 KiB

    const int id  = blockIdx.x;              // 512 blocks, 2 exact rounds
    const int xcd = id & 7;
    const int u   = id >> 3;                 // 0..63
    const int nt  = u >> 4;                  // 0..3 channel tile (256 rows)
    const int ft  = (xcd << 4) | (u & 15);   // 0..127 frame tile, striped/XCD
    const int b   = ft >> 3;
    const int t0  = (ft & 7) << 8;           // frame tile never crosses batch

    const int tid = threadIdx.x;
    const int l   = tid & 63;
    const int wv  = tid >> 6;                // 0..7
    const int ln  = l & 15;
    const int qd  = l >> 4;
    const int wm  = wv & 1;                  // wave M (2)
    const int wn  = wv >> 1;                 // wave N (4)

    // staging: wave wv call c covers rows wv*32 + c*16 + (l>>2), chunk l&3;
    // source pre-swizzled: global chunk = (l&3) ^ ((l>>3)&3)
    const int sr0 = wv * 32 + (l >> 2);
    const int sr1 = sr0 + 16;
    const int sch = ((l & 3) ^ ((l >> 3) & 3)) * 8;
    const unsigned short* wA0 = Wb + (long long)(nt * 256 + sr0) * K_FFT + sch;
    const unsigned short* wA1 = Wb + (long long)(nt * 256 + sr1) * K_FFT + sch;
    const unsigned short* xbase = Xb + (long long)b * XROW;
    const unsigned short* fB0 = xbase + (t0 + sr0) * HOPSZ + sch;
    const unsigned short* fB1 = xbase + (t0 + sr1) * HOPSZ + sch;
    const int d0 = wv * 1024;                // u16 dst offset within slot, call 0
    const int d1 = d0 + 512;                 // call 1

    // ds_read offsets within a half-tile (u16): row*32 + swizzled chunk
    const int cx   = (qd ^ ((ln >> 1) & 3)) * 8;
    const int aoff = (wm * 128 + ln) * 32 + cx;
    const int boff = (wn * 64  + ln) * 32 + cx;

    f32x4 acc[8][4];
    #pragma unroll
    for (int i = 0; i < 8; ++i)
        #pragma unroll
        for (int jn = 0; jn < 4; ++jn) acc[i][jn] = (f32x4){0.f,0.f,0.f,0.f};

    // ---- prologue: stage G0..G5 = t0{A-k0,B-k0,A-k1,B-k1}, t1{A-k0,B-k0}
    gll16(wA0 +  0, S +     0 + d0);  gll16(wA1 +  0, S +     0 + d1);
    gll16(fB0 +  0, S +  8192 + d0);  gll16(fB1 +  0, S +  8192 + d1);
    gll16(wA0 + 32, S + 16384 + d0);  gll16(wA1 + 32, S + 16384 + d1);
    gll16(fB0 + 32, S + 24576 + d0);  gll16(fB1 + 32, S + 24576 + d1);
    gll16(wA0 + 64, S + 32768 + d0);  gll16(wA1 + 64, S + 32768 + d1);
    gll16(fB0 + 64, S + 40960 + d0);  gll16(fB1 + 64, S + 40960 + d1);
    asm volatile("s_waitcnt vmcnt(4)" ::: "memory");   // tile0 ready, t1{h0,h1} in flight
    __builtin_amdgcn_s_barrier();

    #pragma unroll 1
    for (int j = 0; j < 16; ++j) {
        const int bb  = (j & 1) << 15;       // buf of tile j (u16)
        const int bb1 = bb ^ 32768;          // buf of tile j+1
        const int kA  = j * 64 + 96;         // stage koff P0/P1: tile j+1, k1
        const int kB  = j * 64 + 128;        // stage koff P2/P3: tile j+2, k0

        bf16x8 av[8];
        // ================= P0: stage t(j+1) A-k1; compute ks0, N-cols 0-1
        if (j < 15) { gll16(wA0 + kA, S + bb1 + 16384 + d0);
                      gll16(wA1 + kA, S + bb1 + 16384 + d1); }
        {
            const unsigned short* pA = S + bb + aoff;
            const unsigned short* pB = S + bb + 8192 + boff;
            #pragma unroll
            for (int i = 0; i < 8; ++i) av[i] = *(const bf16x8*)(pA + i * 512);
            bf16x8 b0 = *(const bf16x8*)(pB);
            bf16x8 b1 = *(const bf16x8*)(pB + 512);
            __builtin_amdgcn_s_barrier();
            __builtin_amdgcn_s_setprio(1);
            #pragma unroll
            for (int i = 0; i < 8; ++i) {
                acc[i][0] = MFMA(av[i], b0, acc[i][0]);
                acc[i][1] = MFMA(av[i], b1, acc[i][1]);
            }
            __builtin_amdgcn_s_setprio(0);
            __builtin_amdgcn_s_barrier();
        }
        // ================= P1: stage t(j+1) B-k1; compute ks0, N-cols 2-3
        if (j < 15) { gll16(fB0 + kA, S + bb1 + 24576 + d0);
                      gll16(fB1 + kA, S + bb1 + 24576 + d1); }
        {
            const unsigned short* pB = S + bb + 8192 + boff;
            bf16x8 b2 = *(const bf16x8*)(pB + 1024);
            bf16x8 b3 = *(const bf16x8*)(pB + 1536);
            __builtin_amdgcn_s_barrier();
            __builtin_amdgcn_s_setprio(1);
            #pragma unroll
            for (int i = 0; i < 8; ++i) {
                acc[i][2] = MFMA(av[i], b2, acc[i][2]);
                acc[i][3] = MFMA(av[i], b3, acc[i][3]);
            }
            __builtin_amdgcn_s_setprio(0);
            __builtin_amdgcn_s_barrier();
        }
        // ================= P2: stage t(j+2) A-k0; compute ks1, N-cols 0-1
        if (j < 14) { gll16(wA0 + kB, S + bb + d0);
                      gll16(wA1 + kB, S + bb + d1); }
        {
            const unsigned short* pA = S + bb + 16384 + aoff;
            const unsigned short* pB = S + bb + 24576 + boff;
            #pragma unroll
            for (int i = 0; i < 8; ++i) av[i] = *(const bf16x8*)(pA + i * 512);
            bf16x8 b0 = *(const bf16x8*)(pB);
            bf16x8 b1 = *(const bf16x8*)(pB + 512);
            __builtin_amdgcn_s_barrier();
            __builtin_amdgcn_s_setprio(1);
            #pragma unroll
            for (int i = 0; i < 8; ++i) {
                acc[i][0] = MFMA(av[i], b0, acc[i][0]);
                acc[i][1] = MFMA(av[i], b1, acc[i][1]);
            }
            __builtin_amdgcn_s_setprio(0);
            __builtin_amdgcn_s_barrier();
        }
        // ================= P3: stage t(j+2) B-k0; compute ks1, N-cols 2-3
        if (j < 14) { gll16(fB0 + kB, S + bb + 8192 + d0);
                      gll16(fB1 + kB, S + bb + 8192 + d1); }
        {
            const unsigned short* pB = S + bb + 24576 + boff;
            bf16x8 b2 = *(const bf16x8*)(pB + 1024);
            bf16x8 b3 = *(const bf16x8*)(pB + 1536);
            __builtin_amdgcn_s_barrier();
            __builtin_amdgcn_s_setprio(1);
            #pragma unroll
            for (int i = 0; i < 8; ++i) {
                acc[i][2] = MFMA(av[i], b2, acc[i][2]);
                acc[i][3] = MFMA(av[i], b3, acc[i][3]);
            }
            __builtin_amdgcn_s_setprio(0);
            if (j == 14) { asm volatile("s_waitcnt vmcnt(0)" ::: "memory"); }
            else         { asm volatile("s_waitcnt vmcnt(4)" ::: "memory"); }
            __builtin_amdgcn_s_barrier();
        }
    }

    // ---- epilogue: D(16x16) layout: frame = lane&15, ch-sub = qd*4 + reg.
    // m-frag pairs (2p, 2p+1) = (cos, sin) 16-blocks of bin group
    // q = nt*8 + wm*4 + p; bin = q*16 + qd*4 + r.  bin==0 slot: re -> bin 0,
    // im (= cos512 row) -> bin 512.
    float* outb = out + (long long)b * (NCH * T_FRAMES);
    const int tb = t0 + wn * 64 + ln;
    const int binbase = (nt * 8 + wm * 4) * 16 + qd * 4;
    #pragma unroll
    for (int p = 0; p < 4; ++p) {
        #pragma unroll
        for (int jn = 0; jn < 4; ++jn) {
            const int t = tb + jn * 16;
            #pragma unroll
            for (int r = 0; r < 4; ++r) {
                float re = acc[2 * p][jn][r];
                float im = acc[2 * p + 1][jn][r];
                int bin = binbase + p * 16 + r;
                if (bin == 0) {
                    outb[t] = sqrtf(fmaxf(re * re, 1e-12f));
                    outb[(long long)512 * T_FRAMES + t] = sqrtf(fmaxf(im * im, 1e-12f));
                } else {
                    outb[(long long)bin * T_FRAMES + t] =
                        sqrtf(fmaxf(re * re + im * im, 1e-12f));
                }
            }
        }
    }
}

extern "C" void kernel_launch(void* const* d_in, const int* in_sizes, int n_in,
                              void* d_out, int out_size, void* d_ws, size_t ws_size,
                              hipStream_t stream) {
    const float* x  = (const float*)d_in[0];
    const float* wt = (const float*)d_in[1];
    float* out = (float*)d_out;

    unsigned short* Xb = (unsigned short*)d_ws;                             // 16.04 MiB
    unsigned short* Wb = (unsigned short*)((char*)d_ws + (size_t)33554432); // 2 MiB

    prep<<<4608, 256, 0, stream>>>(x, wt, Xb, Wb);
    stft_gemm<<<512, 512, 0, stream>>>(Xb, Wb, out);
}

// Round 2
// 154.087 us; speedup vs baseline: 1.0778x; 1.0016x over previous
//
#include <hip/hip_runtime.h>
#include <stdint.h>

#define SAMPLES   524288
#define BATCH     16
#define T_FRAMES  2048
#define K_FFT     1024
#define HOPSZ     256
#define CACHEPAD  1023
#define NCH       513
#define XROW      525312               // 1023 pad + 524288 samples + 1 spare (16B-aligned rows)

typedef __bf16          bf16x8 __attribute__((ext_vector_type(8)));
typedef float           f32x4  __attribute__((ext_vector_type(4)));
typedef unsigned short  u16x8  __attribute__((ext_vector_type(8)));

__device__ __forceinline__ unsigned short f2bf(float f) {
    union { float f; unsigned u; } v; v.f = f;
    unsigned r = v.u + 0x7fffu + ((v.u >> 16) & 1u);   // round-to-nearest-even
    return (unsigned short)(r >> 16);
}

// ---------- fused prep (verified round 1) --------------------------------
// blocks [0,512):    weight fp32 -> bf16, M=1024 layout: per 32-row group q:
//                    {16 cos rows of bins q*16+r | 16 sin rows}; the sin(bin0)
//                    slot (row 16) holds cos(bin 512) instead (sin0 == 0,
//                    sin512 == 0 exactly).
// blocks [512,4608): x fp32 -> bf16 with 1023-zero left pad per batch row.
__global__ void prep(const float* __restrict__ x, const float* __restrict__ wsrc,
                     unsigned short* __restrict__ Xb, unsigned short* __restrict__ Wb) {
    const int bid = blockIdx.x;
    const int tid = threadIdx.x;
    if (bid < 512) {
        int gid = bid * 256 + tid;            // 0..131071, 8 u16 each
        int m   = gid >> 7;                   // 0..1023 output row
        int kc  = (gid & 127) << 3;           // k chunk base
        int q = m >> 5, h = (m >> 4) & 1, r = m & 15;
        int bin  = q * 16 + r;
        int srow = (h == 0) ? bin : (bin == 0 ? 512 : NCH + bin);
        const float* s = wsrc + (long long)srow * K_FFT + kc;
        f32x4 a = *(const f32x4*)s;
        f32x4 c = *(const f32x4*)(s + 4);
        union { u16x8 v; unsigned short e[8]; } o;
        o.e[0]=f2bf(a[0]); o.e[1]=f2bf(a[1]); o.e[2]=f2bf(a[2]); o.e[3]=f2bf(a[3]);
        o.e[4]=f2bf(c[0]); o.e[5]=f2bf(c[1]); o.e[6]=f2bf(c[2]); o.e[7]=f2bf(c[3]);
        *(u16x8*)(Wb + (long long)m * K_FFT + kc) = o.v;
    } else {
        int id  = bid - 512;
        int bat = id >> 8;
        int bx  = id & 255;
        unsigned short* xbo = Xb + (long long)bat * XROW;
        if (bx == 0) {
            for (int j = tid; j < CACHEPAD; j += 256) xbo[j] = 0;
            if (tid == 0) xbo[XROW - 1] = 0;
        }
        int i0 = (bx * 256 + tid) * 8;
        const float* xb = x + (long long)bat * SAMPLES;
        f32x4 a = *(const f32x4*)&xb[i0];
        f32x4 c = *(const f32x4*)&xb[i0 + 4];
        unsigned short* dst = xbo + CACHEPAD + i0;
        dst[0]=f2bf(a[0]); dst[1]=f2bf(a[1]); dst[2]=f2bf(a[2]); dst[3]=f2bf(a[3]);
        dst[4]=f2bf(c[0]); dst[5]=f2bf(c[1]); dst[6]=f2bf(c[2]); dst[7]=f2bf(c[3]);
    }
}

// ---------- async global -> LDS (16 B/lane, dst = wave-uniform base + lane*16)
__device__ __forceinline__ void gll16(const unsigned short* g, unsigned short* s) {
    __builtin_amdgcn_global_load_lds(
        (const __attribute__((address_space(1))) void*)g,
        (__attribute__((address_space(3))) void*)s,
        16, 0, 0);
}

// ---------- main GEMM + magnitude epilogue --------------------------------
// Proven 128x128 structure (966 TF here): 3 blocks/CU cross-block TLP covers
// barrier drains (beats 1-block/CU 8-phase pipelining on this short-K shape;
// measured round 1: 844 TF). M=1024 weight layout -> zero padding waste.
// Block tile: 128 M-rows x 128 frames, BK = 64, frames im2col'd at stage time.
// LDS layout [row][64] with XOR chunk swizzle (chunk ^= row&7).
// XCD swizzle: 2048 blocks; xcd = id&7 -> fixed 32-ft stripe per XCD
// (~2.1 MB x + 2 MB weights resident per XCD L2).
__global__ __launch_bounds__(256, 3)
void stft_gemm(const unsigned short* __restrict__ Xb,
               const unsigned short* __restrict__ Wb,
               float* __restrict__ out) {
    __shared__ unsigned short Ws[128 * 64];   // 16 KB
    __shared__ unsigned short Fs[128 * 64];   // 16 KB

    const int id  = blockIdx.x;
    const int xcd = id & 7;
    const int idx = id >> 3;        // 0..255
    const int nt  = idx >> 5;       // 0..7  M tile (32 consecutive blocks share it)
    const int ft  = (xcd << 5) | (idx & 31);   // 0..255 frame tile, striped per XCD

    const int tid = threadIdx.x;
    const int l   = tid & 63;
    const int w   = tid >> 6;
    const int ln  = l & 15;
    const int qd  = l >> 4;

    const int b  = ft >> 4;
    const int t0 = (ft & 15) * 128;            // frame tile never crosses a batch

    const unsigned short* xbase = Xb + (long long)b * XROW;

    // ---- staging: wave w stages rows [w*32, w*32+32) of Fs and Ws,
    //      4 gll16 calls each; call c: row = w*32 + c*8 + (l>>3),
    //      lds chunk = l&7 (implicit dst), global chunk = (l&7) ^ (row&7).
    const int srow   = l >> 3;
    const int schunk = l & 7;

    const unsigned short* fsrc[4];
    const unsigned short* wsrc[4];
    unsigned short* fdst[4];
    unsigned short* wdst[4];
    #pragma unroll
    for (int c = 0; c < 4; ++c) {
        int r = w * 32 + c * 8 + srow;
        int gchunk = schunk ^ (r & 7);
        fsrc[c] = xbase + (t0 + r) * HOPSZ + gchunk * 8;       // frame r, k-chunk
        wsrc[c] = Wb + ((long long)(nt * 128 + r)) * K_FFT + gchunk * 8;
        fdst[c] = Fs + (w * 32 + c * 8) * 64;
        wdst[c] = Ws + (w * 32 + c * 8) * 64;
    }

    const int wave_m = w & 1;
    const int wave_n = w >> 1;

    f32x4 acc[4][4];
    #pragma unroll
    for (int i = 0; i < 4; ++i)
        #pragma unroll
        for (int j = 0; j < 4; ++j)
            acc[i][j] = (f32x4){0.f, 0.f, 0.f, 0.f};

    // ds_read offsets: row = base + i*16 + ln (row&7 == ln&7);
    // global chunk wanted = k2*4 + qd -> lds chunk = (k2*4+qd) ^ (ln&7)
    int a_off[4][2], b_off[4][2];
    #pragma unroll
    for (int i = 0; i < 4; ++i)
        #pragma unroll
        for (int k2 = 0; k2 < 2; ++k2) {
            int ck = ((k2 * 4 + qd) ^ (ln & 7)) * 8;
            a_off[i][k2] = (wave_m * 64 + i * 16 + ln) * 64 + ck;
            b_off[i][k2] = (wave_n * 64 + i * 16 + ln) * 64 + ck;
        }

    for (int kk = 0; kk < K_FFT; kk += 64) {
        #pragma unroll
        for (int c = 0; c < 4; ++c) gll16(fsrc[c] + kk, fdst[c]);
        #pragma unroll
        for (int c = 0; c < 4; ++c) gll16(wsrc[c] + kk, wdst[c]);
        __syncthreads();

        #pragma unroll
        for (int k2 = 0; k2 < 2; ++k2) {
            bf16x8 av[4], bv[4];
            #pragma unroll
            for (int i = 0; i < 4; ++i) av[i] = *(const bf16x8*)&Ws[a_off[i][k2]];
            #pragma unroll
            for (int j = 0; j < 4; ++j) bv[j] = *(const bf16x8*)&Fs[b_off[j][k2]];
            #pragma unroll
            for (int i = 0; i < 4; ++i)
                #pragma unroll
                for (int j = 0; j < 4; ++j)
                    acc[i][j] = __builtin_amdgcn_mfma_f32_16x16x32_bf16(av[i], bv[j], acc[i][j], 0, 0, 0);
        }
        __syncthreads();
    }

    // ---- epilogue: mag = sqrt(max(re^2+im^2, 1e-12)), coalesced stores ----
    // D layout (16x16x32): frame = lane&15, m-sub = qd*4 + reg.
    // A-frag i = 2p+h: h=0 cos, h=1 sin of bin group q = nt*4 + wave_m*2 + p.
    // bin==0 slot: re -> bin 0, im (= cos512 row) -> bin 512.
    float* outb = out + (long long)b * (NCH * T_FRAMES);
    #pragma unroll
    for (int p = 0; p < 2; ++p) {
        #pragma unroll
        for (int j = 0; j < 4; ++j) {
            const int t = t0 + wave_n * 64 + j * 16 + ln;
            #pragma unroll
            for (int r = 0; r < 4; ++r) {
                float re  = acc[2 * p][j][r];
                float im  = acc[2 * p + 1][j][r];
                int bin = (nt * 4 + wave_m * 2 + p) * 16 + qd * 4 + r;
                if (bin == 0) {
                    outb[t] = sqrtf(fmaxf(re * re, 1e-12f));
                    outb[(long long)512 * T_FRAMES + t] = sqrtf(fmaxf(im * im, 1e-12f));
                } else {
                    outb[(long long)bin * T_FRAMES + t] =
                        sqrtf(fmaxf(re * re + im * im, 1e-12f));
                }
            }
        }
    }
}

extern "C" void kernel_launch(void* const* d_in, const int* in_sizes, int n_in,
                              void* d_out, int out_size, void* d_ws, size_t ws_size,
                              hipStream_t stream) {
    const float* x  = (const float*)d_in[0];
    const float* wt = (const float*)d_in[1];
    float* out = (float*)d_out;

    unsigned short* Xb = (unsigned short*)d_ws;                             // 16.04 MiB
    unsigned short* Wb = (unsigned short*)((char*)d_ws + (size_t)33554432); // 2 MiB

    prep<<<4608, 256, 0, stream>>>(x, wt, Xb, Wb);
    stft_gemm<<<2048, 256, 0, stream>>>(Xb, Wb, out);
}

// Round 3
// 153.106 us; speedup vs baseline: 1.0847x; 1.0064x over previous
//
#include <hip/hip_runtime.h>
#include <stdint.h>

#define SAMPLES   524288
#define BATCH     16
#define T_FRAMES  2048
#define K_FFT     1024
#define HOPSZ     256
#define CACHEPAD  1023
#define NCH       513
#define XROW      525312               // 1023 pad + 524288 samples + 1 spare (16B-aligned rows)

typedef __bf16          bf16x8 __attribute__((ext_vector_type(8)));
typedef float           f32x4  __attribute__((ext_vector_type(4)));
typedef unsigned short  u16x8  __attribute__((ext_vector_type(8)));

__device__ __forceinline__ unsigned short f2bf(float f) {
    union { float f; unsigned u; } v; v.f = f;
    unsigned r = v.u + 0x7fffu + ((v.u >> 16) & 1u);   // round-to-nearest-even
    return (unsigned short)(r >> 16);
}

// ---------- fused prep (verified rounds 1-2) ------------------------------
// blocks [0,512):    weight fp32 -> bf16, M=1024 layout: per 32-row group q:
//                    {16 cos rows of bins q*16+r | 16 sin rows}; sin(bin0)
//                    slot holds cos(bin 512) (sin0 == 0, sin512 == 0).
// blocks [512,4608): x fp32 -> bf16 with 1023-zero left pad per batch row.
__global__ void prep(const float* __restrict__ x, const float* __restrict__ wsrc,
                     unsigned short* __restrict__ Xb, unsigned short* __restrict__ Wb) {
    const int bid = blockIdx.x;
    const int tid = threadIdx.x;
    if (bid < 512) {
        int gid = bid * 256 + tid;            // 0..131071, 8 u16 each
        int m   = gid >> 7;                   // 0..1023 output row
        int kc  = (gid & 127) << 3;           // k chunk base
        int q = m >> 5, h = (m >> 4) & 1, r = m & 15;
        int bin  = q * 16 + r;
        int srow = (h == 0) ? bin : (bin == 0 ? 512 : NCH + bin);
        const float* s = wsrc + (long long)srow * K_FFT + kc;
        f32x4 a = *(const f32x4*)s;
        f32x4 c = *(const f32x4*)(s + 4);
        union { u16x8 v; unsigned short e[8]; } o;
        o.e[0]=f2bf(a[0]); o.e[1]=f2bf(a[1]); o.e[2]=f2bf(a[2]); o.e[3]=f2bf(a[3]);
        o.e[4]=f2bf(c[0]); o.e[5]=f2bf(c[1]); o.e[6]=f2bf(c[2]); o.e[7]=f2bf(c[3]);
        *(u16x8*)(Wb + (long long)m * K_FFT + kc) = o.v;
    } else {
        int id  = bid - 512;
        int bat = id >> 8;
        int bx  = id & 255;
        unsigned short* xbo = Xb + (long long)bat * XROW;
        if (bx == 0) {
            for (int j = tid; j < CACHEPAD; j += 256) xbo[j] = 0;
            if (tid == 0) xbo[XROW - 1] = 0;
        }
        int i0 = (bx * 256 + tid) * 8;
        const float* xb = x + (long long)bat * SAMPLES;
        f32x4 a = *(const f32x4*)&xb[i0];
        f32x4 c = *(const f32x4*)&xb[i0 + 4];
        unsigned short* dst = xbo + CACHEPAD + i0;
        dst[0]=f2bf(a[0]); dst[1]=f2bf(a[1]); dst[2]=f2bf(a[2]); dst[3]=f2bf(a[3]);
        dst[4]=f2bf(c[0]); dst[5]=f2bf(c[1]); dst[6]=f2bf(c[2]); dst[7]=f2bf(c[3]);
    }
}

// ---------- async global -> LDS (16 B/lane, dst = wave-uniform base + lane*16)
__device__ __forceinline__ void gll16(const unsigned short* g, unsigned short* s) {
    __builtin_amdgcn_global_load_lds(
        (const __attribute__((address_space(1))) void*)g,
        (__attribute__((address_space(3))) void*)s,
        16, 0, 0);
}

#define MFMA(a,b,c) __builtin_amdgcn_mfma_f32_16x16x32_bf16((a),(b),(c),0,0,0)

// ---------- main GEMM: persistent 256x512 per block -----------------------
// 256x256 tile, BK=64, 8 waves (2M x 4N), m201 8-phase schedule (round-1
// verified ledger), but each block processes TWO adjacent 256-frame tiles
// sharing the same weight panel: K-loop = 32 tiles in one pass (B switches
// at j=16, A k-offset wraps mod 16, acc flushed mid-kernel). Grid = 4 nt x
// 64 frame-pairs = 256 blocks = EXACTLY ONE ROUND, 1 block/CU -> one
// prologue fill + one tail instead of two (round-1 failure mode).
// LDS 128KB = 2 bufs x 4 half-tiles(16KB): [A-k0 | B-k0 | A-k1 | B-k1].
// vmcnt(4) once per tile; vmcnt(0) only at j==30 (prefetch stops).
__global__ __launch_bounds__(512, 2)
void stft_gemm(const unsigned short* __restrict__ Xb,
               const unsigned short* __restrict__ Wb,
               float* __restrict__ out) {
    __shared__ unsigned short S[65536];      // 128 KiB

    const int id  = blockIdx.x;              // 256 blocks, 1 per CU
    const int xcd = id & 7;
    const int u   = id >> 3;                 // 0..31
    const int nt  = u >> 3;                  // 0..3 channel tile (256 rows)
    const int fp  = (xcd << 3) | (u & 7);    // 0..63 frame-pair, striped/XCD
    const int b   = fp >> 2;                 // batch
    const int offF = (fp & 3) << 9;          // frame offset in batch (512-frame pair)

    const int tid = threadIdx.x;
    const int l   = tid & 63;
    const int wv  = tid >> 6;                // 0..7
    const int ln  = l & 15;
    const int qd  = l >> 4;
    const int wm  = wv & 1;                  // wave M (2)
    const int wn  = wv >> 1;                 // wave N (4)

    // staging: wave wv call c covers rows wv*32 + c*16 + (l>>2), chunk l&3;
    // source pre-swizzled: global chunk = (l&3) ^ ((l>>3)&3)
    const int sr0 = wv * 32 + (l >> 2);
    const int sr1 = sr0 + 16;
    const int sch = ((l & 3) ^ ((l >> 3) & 3)) * 8;
    const unsigned short* wA0 = Wb + (long long)(nt * 256 + sr0) * K_FFT + sch;
    const unsigned short* wA1 = Wb + (long long)(nt * 256 + sr1) * K_FFT + sch;
    const unsigned short* xbase = Xb + (long long)b * XROW;
    const unsigned short* fB0 = xbase + (offF + sr0) * HOPSZ + sch;
    const unsigned short* fB1 = xbase + (offF + sr1) * HOPSZ + sch;
    const int d0 = wv * 1024;                // u16 dst offset within slot, call 0
    const int d1 = d0 + 512;                 // call 1

    // ds_read offsets within a half-tile (u16): row*32 + swizzled chunk
    const int cx   = (qd ^ ((ln >> 1) & 3)) * 8;
    const int aoff = (wm * 128 + ln) * 32 + cx;
    const int boff = (wn * 64  + ln) * 32 + cx;

    f32x4 acc[8][4];
    #pragma unroll
    for (int i = 0; i < 8; ++i)
        #pragma unroll
        for (int jn = 0; jn < 4; ++jn) acc[i][jn] = (f32x4){0.f,0.f,0.f,0.f};

    // ---- prologue: stage t0{A-k0,B-k0,A-k1,B-k1}, t1{A-k0,B-k0}
    gll16(wA0 +  0, S +     0 + d0);  gll16(wA1 +  0, S +     0 + d1);
    gll16(fB0 +  0, S +  8192 + d0);  gll16(fB1 +  0, S +  8192 + d1);
    gll16(wA0 + 32, S + 16384 + d0);  gll16(wA1 + 32, S + 16384 + d1);
    gll16(fB0 + 32, S + 24576 + d0);  gll16(fB1 + 32, S + 24576 + d1);
    gll16(wA0 + 64, S + 32768 + d0);  gll16(wA1 + 64, S + 32768 + d1);
    gll16(fB0 + 64, S + 40960 + d0);  gll16(fB1 + 64, S + 40960 + d1);
    asm volatile("s_waitcnt vmcnt(4)" ::: "memory");   // tile0 ready, t1{h0,h1} in flight
    __builtin_amdgcn_s_barrier();

    float* outb = out + (long long)b * (NCH * T_FRAMES);
    const int binbase = (nt * 8 + wm * 4) * 16 + qd * 4;

    #pragma unroll 1
    for (int j = 0; j < 32; ++j) {
        const int bb  = (j & 1) << 15;       // buf of tile j (u16)
        const int bb1 = bb ^ 32768;          // buf of tile j+1
        const int s1  = j + 1;
        const int s2  = j + 2;
        const int kA  = ((s1 & 15) << 6) + 32;   // tile j+1, k1 half
        const int kB  = (s2 & 15) << 6;          // tile j+2, k0 half
        const int ho1 = (s1 & 16) << 12;         // B frame-half of tile j+1 (u16)
        const int ho2 = (s2 & 16) << 12;         // B frame-half of tile j+2

        bf16x8 av[8];
        // ================= P0: stage t(j+1) A-k1; compute ks0, N-cols 0-1
        if (j < 31) { gll16(wA0 + kA, S + bb1 + 16384 + d0);
                      gll16(wA1 + kA, S + bb1 + 16384 + d1); }
        {
            const unsigned short* pA = S + bb + aoff;
            const unsigned short* pB = S + bb + 8192 + boff;
            #pragma unroll
            for (int i = 0; i < 8; ++i) av[i] = *(const bf16x8*)(pA + i * 512);
            bf16x8 b0 = *(const bf16x8*)(pB);
            bf16x8 b1 = *(const bf16x8*)(pB + 512);
            __builtin_amdgcn_s_barrier();
            __builtin_amdgcn_s_setprio(1);
            #pragma unroll
            for (int i = 0; i < 8; ++i) {
                acc[i][0] = MFMA(av[i], b0, acc[i][0]);
                acc[i][1] = MFMA(av[i], b1, acc[i][1]);
            }
            __builtin_amdgcn_s_setprio(0);
            __builtin_amdgcn_s_barrier();
        }
        // ================= P1: stage t(j+1) B-k1; compute ks0, N-cols 2-3
        if (j < 31) { gll16(fB0 + ho1 + kA, S + bb1 + 24576 + d0);
                      gll16(fB1 + ho1 + kA, S + bb1 + 24576 + d1); }
        {
            const unsigned short* pB = S + bb + 8192 + boff;
            bf16x8 b2 = *(const bf16x8*)(pB + 1024);
            bf16x8 b3 = *(const bf16x8*)(pB + 1536);
            __builtin_amdgcn_s_barrier();
            __builtin_amdgcn_s_setprio(1);
            #pragma unroll
            for (int i = 0; i < 8; ++i) {
                acc[i][2] = MFMA(av[i], b2, acc[i][2]);
                acc[i][3] = MFMA(av[i], b3, acc[i][3]);
            }
            __builtin_amdgcn_s_setprio(0);
            __builtin_amdgcn_s_barrier();
        }
        // ================= P2: stage t(j+2) A-k0; compute ks1, N-cols 0-1
        if (j < 30) { gll16(wA0 + kB, S + bb + d0);
                      gll16(wA1 + kB, S + bb + d1); }
        {
            const unsigned short* pA = S + bb + 16384 + aoff;
            const unsigned short* pB = S + bb + 24576 + boff;
            #pragma unroll
            for (int i = 0; i < 8; ++i) av[i] = *(const bf16x8*)(pA + i * 512);
            bf16x8 b0 = *(const bf16x8*)(pB);
            bf16x8 b1 = *(const bf16x8*)(pB + 512);
            __builtin_amdgcn_s_barrier();
            __builtin_amdgcn_s_setprio(1);
            #pragma unroll
            for (int i = 0; i < 8; ++i) {
                acc[i][0] = MFMA(av[i], b0, acc[i][0]);
                acc[i][1] = MFMA(av[i], b1, acc[i][1]);
            }
            __builtin_amdgcn_s_setprio(0);
            __builtin_amdgcn_s_barrier();
        }
        // ================= P3: stage t(j+2) B-k0; compute ks1, N-cols 2-3
        if (j < 30) { gll16(fB0 + ho2 + kB, S + bb + 8192 + d0);
                      gll16(fB1 + ho2 + kB, S + bb + 8192 + d1); }
        {
            const unsigned short* pB = S + bb + 24576 + boff;
            bf16x8 b2 = *(const bf16x8*)(pB + 1024);
            bf16x8 b3 = *(const bf16x8*)(pB + 1536);
            __builtin_amdgcn_s_barrier();
            __builtin_amdgcn_s_setprio(1);
            #pragma unroll
            for (int i = 0; i < 8; ++i) {
                acc[i][2] = MFMA(av[i], b2, acc[i][2]);
                acc[i][3] = MFMA(av[i], b3, acc[i][3]);
            }
            __builtin_amdgcn_s_setprio(0);
            if (j == 30) { asm volatile("s_waitcnt vmcnt(0)" ::: "memory"); }
            else         { asm volatile("s_waitcnt vmcnt(4)" ::: "memory"); }
            __builtin_amdgcn_s_barrier();
        }

        // ---- mid-kernel flush: ft0 done after tile 15; write + zero acc.
        // Stores retire into L2; subsequent counted vmcnt(4) drains them
        // alongside the in-flight prefetches (correct: waits for >=tile j+1).
        if (j == 15) {
            const int tb = offF + wn * 64 + ln;
            #pragma unroll
            for (int p = 0; p < 4; ++p) {
                #pragma unroll
                for (int jn = 0; jn < 4; ++jn) {
                    const int t = tb + jn * 16;
                    #pragma unroll
                    for (int r = 0; r < 4; ++r) {
                        float re = acc[2 * p][jn][r];
                        float im = acc[2 * p + 1][jn][r];
                        int bin = binbase + p * 16 + r;
                        if (bin == 0) {
                            outb[t] = sqrtf(fmaxf(re * re, 1e-12f));
                            outb[(long long)512 * T_FRAMES + t] = sqrtf(fmaxf(im * im, 1e-12f));
                        } else {
                            outb[(long long)bin * T_FRAMES + t] =
                                sqrtf(fmaxf(re * re + im * im, 1e-12f));
                        }
                    }
                }
            }
            #pragma unroll
            for (int i = 0; i < 8; ++i)
                #pragma unroll
                for (int jn = 0; jn < 4; ++jn) acc[i][jn] = (f32x4){0.f,0.f,0.f,0.f};
        }
    }

    // ---- final flush: ft1 (frames offF+256 .. offF+511) ------------------
    {
        const int tb = offF + 256 + wn * 64 + ln;
        #pragma unroll
        for (int p = 0; p < 4; ++p) {
            #pragma unroll
            for (int jn = 0; jn < 4; ++jn) {
                const int t = tb + jn * 16;
                #pragma unroll
                for (int r = 0; r < 4; ++r) {
                    float re = acc[2 * p][jn][r];
                    float im = acc[2 * p + 1][jn][r];
                    int bin = binbase + p * 16 + r;
                    if (bin == 0) {
                        outb[t] = sqrtf(fmaxf(re * re, 1e-12f));
                        outb[(long long)512 * T_FRAMES + t] = sqrtf(fmaxf(im * im, 1e-12f));
                    } else {
                        outb[(long long)bin * T_FRAMES + t] =
                            sqrtf(fmaxf(re * re + im * im, 1e-12f));
                    }
                }
            }
        }
    }
}

extern "C" void kernel_launch(void* const* d_in, const int* in_sizes, int n_in,
                              void* d_out, int out_size, void* d_ws, size_t ws_size,
                              hipStream_t stream) {
    const float* x  = (const float*)d_in[0];
    const float* wt = (const float*)d_in[1];
    float* out = (float*)d_out;

    unsigned short* Xb = (unsigned short*)d_ws;                             // 16.04 MiB
    unsigned short* Wb = (unsigned short*)((char*)d_ws + (size_t)33554432); // 2 MiB

    prep<<<4608, 256, 0, stream>>>(x, wt, Xb, Wb);
    stft_gemm<<<256, 512, 0, stream>>>(Xb, Wb, out);
}